// Round 8
// baseline (891.684 us; speedup 1.0000x reference)
//
#include <hip/hip_runtime.h>
#include <hip/hip_bf16.h>

#define KS 5
#define NCH 32
#define IMH 256
#define IMW 256
#define TW 32
#define TH 8
#define HALO_W (TW + 4)
#define HALO_H (TH + 4)
#define HW (IMH * IMW)
#define OC_CHUNK 8

// Both kernels: stage-chunk 4 channels -> 7 loads/thread prefetch pipeline
#define CHUNK 4
#define NCHUNK (NCH / CHUNK)
#define TILE_ELEMS (CHUNK * HALO_H * HALO_W)
#define LOADS ((TILE_ELEMS + 255) / 256)   // 7

__device__ __forceinline__ float sigmoidf_(float x) {
    return 1.0f / (1.0f + __expf(-x));
}

// ---------------------------------------------------------------------------
// Kernel A: upper path, T14 async-STAGE pipeline at CHUNK=4 (B's proven
// register budget; R7 lesson: LOADS=14 pipeline -> 208 VGPR, occupancy 11%).
// ---------------------------------------------------------------------------
__global__ __launch_bounds__(256) void cika_ksa_kernel(
    const float* __restrict__ upper,
    const float* __restrict__ ksa_dw_w, const float* __restrict__ ksa_dw_b,
    const float* __restrict__ ksa_m1_w, const float* __restrict__ ksa_m1_b,
    const float* __restrict__ ksa_m2_w, const float* __restrict__ ksa_m2_b,
    const float* __restrict__ up_dw_w, const float* __restrict__ up_dw_b,
    float* __restrict__ ws_dwu,   // (N, 32, H, W)
    float* __restrict__ ws_ksa)   // (N, 25, H, W)
{
    __shared__ float tile[TILE_ELEMS];

    const int tid = threadIdx.x;
    const int tx = tid & (TW - 1);
    const int ty = tid >> 5;
    const int tile_x = blockIdx.x * TW;
    const int tile_y = blockIdx.y * TH;
    const int n = blockIdx.z;
    const int x = tile_x + tx, y = tile_y + ty;
    const int pix = y * IMW + x;

    const float* upb = upper + (size_t)n * NCH * HW;
    float* dwu_out = ws_dwu + (size_t)n * NCH * HW + pix;

    // hoisted staging geometry (constant across chunks)
    int goff[LOADS];
    bool gok[LOADS];
    #pragma unroll
    for (int l = 0; l < LOADS; ++l) {
        const int idx = tid + l * 256;
        int c = idx / (HALO_H * HALO_W);
        int r = idx - c * (HALO_H * HALO_W);
        int hy = r / HALO_W, hx = r - hy * HALO_W;
        int gy = tile_y + hy - 2, gx = tile_x + hx - 2;
        gok[l] = (idx < TILE_ELEMS) && (gy >= 0) && (gy < IMH) && (gx >= 0) && (gx < IMW);
        goff[l] = c * HW + gy * IMW + gx;
    }

    float pre[LOADS];
    #pragma unroll
    for (int l = 0; l < LOADS; ++l)
        pre[l] = gok[l] ? upb[(size_t)0 + goff[l]] : 0.0f;

    float dwu_ksa[NCH];

    #pragma unroll
    for (int ck = 0; ck < NCHUNK; ++ck) {
        __syncthreads();
        #pragma unroll
        for (int l = 0; l < LOADS; ++l) {
            const int idx = tid + l * 256;
            if (idx < TILE_ELEMS) tile[idx] = pre[l];
        }
        __syncthreads();
        if (ck + 1 < NCHUNK) {
            const size_t base = (size_t)(ck + 1) * CHUNK * HW;
            #pragma unroll
            for (int l = 0; l < LOADS; ++l)
                pre[l] = gok[l] ? upb[base + goff[l]] : 0.0f;
        }
        const int c0 = ck * CHUNK;
        #pragma unroll
        for (int cc = 0; cc < CHUNK; ++cc) {
            const int c = c0 + cc;
            float ak = ksa_dw_b[c];
            float au = up_dw_b[c];
            const float* tp = tile + cc * (HALO_H * HALO_W) + ty * HALO_W + tx;
            #pragma unroll
            for (int i = 0; i < KS; ++i)
                #pragma unroll
                for (int j = 0; j < KS; ++j) {
                    float wv = tp[i * HALO_W + j];
                    ak = fmaf(wv, ksa_dw_w[c * 25 + i * KS + j], ak);
                    au = fmaf(wv, up_dw_w[c * 25 + i * KS + j], au);
                }
            dwu_ksa[c] = fmaxf(ak, 0.0f);
            dwu_out[(size_t)c * HW] = au;
        }
    }

    // KSA MLP: 32 -> 50 (relu) -> 25 (sigmoid)
    float ksa[25];
    #pragma unroll
    for (int k = 0; k < 25; ++k) ksa[k] = ksa_m2_b[k];
    for (int h = 0; h < 50; ++h) {
        float hv = ksa_m1_b[h];
        #pragma unroll
        for (int c = 0; c < NCH; ++c)
            hv = fmaf(ksa_m1_w[h * NCH + c], dwu_ksa[c], hv);
        hv = fmaxf(hv, 0.0f);
        #pragma unroll
        for (int k = 0; k < 25; ++k)
            ksa[k] = fmaf(ksa_m2_w[k * 50 + h], hv, ksa[k]);
    }

    float* ksa_out = ws_ksa + (size_t)n * 25 * HW + pix;
    #pragma unroll
    for (int k = 0; k < 25; ++k)
        ksa_out[(size_t)k * HW] = sigmoidf_(ksa[k]);
}

// ---------------------------------------------------------------------------
// Kernel B: byte-identical to R7 (T14 pipeline, CHUNK=4 — proven ~2x win).
// ---------------------------------------------------------------------------
__global__ __launch_bounds__(256) void cika_low_up_kernel(
    const float* __restrict__ lower,
    const float* __restrict__ ws_ksa, const float* __restrict__ ws_dwu,
    const float* __restrict__ kca_dw_w, const float* __restrict__ kca_dw_b,
    const float* __restrict__ kca_m1_w, const float* __restrict__ kca_m1_b,
    const float* __restrict__ kca_m2_w, const float* __restrict__ kca_m2_b,
    const float* __restrict__ low_dyn_w, const float* __restrict__ low_dyn_b,
    const float* __restrict__ low_pw_w, const float* __restrict__ low_pw_b,
    const float* __restrict__ up_pw_w, const float* __restrict__ up_pw_b,
    float* __restrict__ out_low, float* __restrict__ out_up)
{
    __shared__ float tile[TILE_ELEMS];
    __shared__ __hip_bfloat16 td_lds[NCH][256];   // dynamic-dw result
    __shared__ __hip_bfloat16 dwl_lds[NCH][256];  // relu(kca-dw) result

    const int tid = threadIdx.x;
    const int tx = tid & (TW - 1);
    const int ty = tid >> 5;
    const int tile_x = blockIdx.x * TW;
    const int tile_y = blockIdx.y * TH;
    const int n = blockIdx.z;
    const int x = tile_x + tx, y = tile_y + ty;
    const int pix = y * IMW + x;

    const float* lob = lower + (size_t)n * NCH * HW;

    // hoisted staging geometry
    int goff[LOADS];
    bool gok[LOADS];
    #pragma unroll
    for (int l = 0; l < LOADS; ++l) {
        const int idx = tid + l * 256;
        int c = idx / (HALO_H * HALO_W);
        int r = idx - c * (HALO_H * HALO_W);
        int hy = r / HALO_W, hx = r - hy * HALO_W;
        int gy = tile_y + hy - 2, gx = tile_x + hx - 2;
        gok[l] = (idx < TILE_ELEMS) && (gy >= 0) && (gy < IMH) && (gx >= 0) && (gx < IMW);
        goff[l] = c * HW + gy * IMW + gx;
    }

    // ksa attention weights for this pixel (live through the lower pass only)
    float ksa[25];
    {
        const float* kp = ws_ksa + (size_t)n * 25 * HW + pix;
        #pragma unroll
        for (int k = 0; k < 25; ++k) ksa[k] = kp[(size_t)k * HW];
    }

    float pre[LOADS];
    #pragma unroll
    for (int l = 0; l < LOADS; ++l)
        pre[l] = gok[l] ? lob[(size_t)0 + goff[l]] : 0.0f;

    // ---- lower pass; results go straight to LDS ----
    #pragma unroll
    for (int ck = 0; ck < NCHUNK; ++ck) {
        __syncthreads();
        #pragma unroll
        for (int l = 0; l < LOADS; ++l) {
            const int idx = tid + l * 256;
            if (idx < TILE_ELEMS) tile[idx] = pre[l];
        }
        __syncthreads();
        if (ck + 1 < NCHUNK) {
            const size_t base = (size_t)(ck + 1) * CHUNK * HW;
            #pragma unroll
            for (int l = 0; l < LOADS; ++l)
                pre[l] = gok[l] ? lob[base + goff[l]] : 0.0f;
        }
        const int c0 = ck * CHUNK;
        #pragma unroll
        for (int cc = 0; cc < CHUNK; ++cc) {
            const int c = c0 + cc;
            float ad = kca_dw_b[c];
            float td = low_dyn_b[c];
            const float* tp = tile + cc * (HALO_H * HALO_W) + ty * HALO_W + tx;
            #pragma unroll
            for (int i = 0; i < KS; ++i)
                #pragma unroll
                for (int j = 0; j < KS; ++j) {
                    float wv = tp[i * HALO_W + j];
                    ad = fmaf(wv, kca_dw_w[c * 25 + i * KS + j], ad);
                    td = fmaf(wv * low_dyn_w[c * 25 + i * KS + j], ksa[i * KS + j], td);
                }
            dwl_lds[c][tid] = __float2bfloat16(fmaxf(ad, 0.0f));
            td_lds[c][tid]  = __float2bfloat16(td);
        }
    }
    // td_lds/dwl_lds are written and read only by column [.][tid] -> no barrier.

    // ---- out_low pointwise, chunked over output channels ----
    {
        float* ol = out_low + (size_t)n * NCH * HW + pix;
        #pragma unroll
        for (int oc = 0; oc < NCH / OC_CHUNK; ++oc) {
            float acc[OC_CHUNK];
            #pragma unroll
            for (int oo = 0; oo < OC_CHUNK; ++oo)
                acc[oo] = low_pw_b[oc * OC_CHUNK + oo];
            #pragma unroll
            for (int c = 0; c < NCH; ++c) {
                float v = __bfloat162float(td_lds[c][tid]);
                #pragma unroll
                for (int oo = 0; oo < OC_CHUNK; ++oo)
                    acc[oo] = fmaf(low_pw_w[(oc * OC_CHUNK + oo) * NCH + c], v, acc[oo]);
            }
            #pragma unroll
            for (int oo = 0; oo < OC_CHUNK; ++oo)
                ol[(size_t)(oc * OC_CHUNK + oo) * HW] = acc[oo];
        }
    }

    // ---- KCA MLP (stream dwl from LDS) ----
    float kca[NCH];
    {
        float hv[8];
        #pragma unroll
        for (int h = 0; h < 8; ++h) hv[h] = kca_m1_b[h];
        #pragma unroll
        for (int c = 0; c < NCH; ++c) {
            float v = __bfloat162float(dwl_lds[c][tid]);
            #pragma unroll
            for (int h = 0; h < 8; ++h)
                hv[h] = fmaf(kca_m1_w[h * NCH + c], v, hv[h]);
        }
        #pragma unroll
        for (int h = 0; h < 8; ++h) hv[h] = fmaxf(hv[h], 0.0f);
        #pragma unroll
        for (int k = 0; k < NCH; ++k) {
            float a = kca_m2_b[k];
            #pragma unroll
            for (int h = 0; h < 8; ++h)
                a = fmaf(kca_m2_w[k * 8 + h], hv[h], a);
            kca[k] = sigmoidf_(a);
        }
    }

    // ---- up path: gate dwu by kca, chunked pointwise ----
    float t2[NCH];
    {
        const float* dup = ws_dwu + (size_t)n * NCH * HW + pix;
        #pragma unroll
        for (int c = 0; c < NCH; ++c)
            t2[c] = dup[(size_t)c * HW] * kca[c];
    }
    {
        float* ou = out_up + (size_t)n * NCH * HW + pix;
        #pragma unroll
        for (int oc = 0; oc < NCH / OC_CHUNK; ++oc) {
            float acc[OC_CHUNK];
            #pragma unroll
            for (int oo = 0; oo < OC_CHUNK; ++oo)
                acc[oo] = up_pw_b[oc * OC_CHUNK + oo];
            #pragma unroll
            for (int c = 0; c < NCH; ++c) {
                #pragma unroll
                for (int oo = 0; oo < OC_CHUNK; ++oo)
                    acc[oo] = fmaf(up_pw_w[(oc * OC_CHUNK + oo) * NCH + c], t2[c], acc[oo]);
            }
            #pragma unroll
            for (int oo = 0; oo < OC_CHUNK; ++oo)
                ou[(size_t)(oc * OC_CHUNK + oo) * HW] = acc[oo];
        }
    }
}

extern "C" void kernel_launch(void* const* d_in, const int* in_sizes, int n_in,
                              void* d_out, int out_size, void* d_ws, size_t ws_size,
                              hipStream_t stream) {
    const float* lower    = (const float*)d_in[0];
    const float* upper    = (const float*)d_in[1];
    const float* kca_dw_w = (const float*)d_in[2];
    const float* kca_dw_b = (const float*)d_in[3];
    const float* kca_m1_w = (const float*)d_in[4];
    const float* kca_m1_b = (const float*)d_in[5];
    const float* kca_m2_w = (const float*)d_in[6];
    const float* kca_m2_b = (const float*)d_in[7];
    const float* ksa_dw_w = (const float*)d_in[8];
    const float* ksa_dw_b = (const float*)d_in[9];
    const float* ksa_m1_w = (const float*)d_in[10];
    const float* ksa_m1_b = (const float*)d_in[11];
    const float* ksa_m2_w = (const float*)d_in[12];
    const float* ksa_m2_b = (const float*)d_in[13];
    const float* low_dyn_w = (const float*)d_in[14];
    const float* low_dyn_b = (const float*)d_in[15];
    const float* low_pw_w  = (const float*)d_in[16];
    const float* low_pw_b  = (const float*)d_in[17];
    const float* up_dw_w   = (const float*)d_in[18];
    const float* up_dw_b   = (const float*)d_in[19];
    const float* up_pw_w   = (const float*)d_in[20];
    const float* up_pw_b   = (const float*)d_in[21];

    const int N = in_sizes[0] / (NCH * HW);
    float* out_low = (float*)d_out;
    float* out_up  = (float*)d_out + (size_t)N * NCH * HW;

    float* ws_dwu = (float*)d_ws;                       // N*32*HW floats
    float* ws_ksa = ws_dwu + (size_t)N * NCH * HW;      // N*25*HW floats

    dim3 grid(IMW / TW, IMH / TH, N);

    cika_ksa_kernel<<<grid, dim3(256), 0, stream>>>(
        upper,
        ksa_dw_w, ksa_dw_b, ksa_m1_w, ksa_m1_b, ksa_m2_w, ksa_m2_b,
        up_dw_w, up_dw_b,
        ws_dwu, ws_ksa);

    cika_low_up_kernel<<<grid, dim3(256), 0, stream>>>(
        lower, ws_ksa, ws_dwu,
        kca_dw_w, kca_dw_b, kca_m1_w, kca_m1_b, kca_m2_w, kca_m2_b,
        low_dyn_w, low_dyn_b, low_pw_w, low_pw_b,
        up_pw_w, up_pw_b,
        out_low, out_up);
}

// Round 9
// 199.323 us; speedup vs baseline: 4.4736x; 4.4736x over previous
//
#include <hip/hip_runtime.h>
#include <hip/hip_bf16.h>

#define KS 5
#define NCH 32
#define IMH 256
#define IMW 256
#define TW 32
#define TH 8
#define HALO_W (TW + 4)
#define HALO_H (TH + 4)
#define HW (IMH * IMW)
#define OC_CHUNK 8

// Both kernels: stage-chunk 4 channels -> 7 loads/thread prefetch pipeline
#define CHUNK 4
#define NCHUNK (NCH / CHUNK)
#define TILE_ELEMS (CHUNK * HALO_H * HALO_W)
#define LOADS ((TILE_ELEMS + 255) / 256)   // 7

__device__ __forceinline__ float sigmoidf_(float x) {
    return 1.0f / (1.0f + __expf(-x));
}

// ---------------------------------------------------------------------------
// Kernel A: upper path, T14 pipeline at CHUNK=4. R8 lesson: a register array
// incrementally WRITTEN across the unrolled staging loop (dwu_ksa) blows the
// allocator (256 VGPR + spill). Fix: retire relu(ak) to LDS per channel
// (per-thread column, B's idiom); read back into a fresh array AFTER the
// loop so live ranges don't overlap the pipeline.
// ---------------------------------------------------------------------------
__global__ __launch_bounds__(256) void cika_ksa_kernel(
    const float* __restrict__ upper,
    const float* __restrict__ ksa_dw_w, const float* __restrict__ ksa_dw_b,
    const float* __restrict__ ksa_m1_w, const float* __restrict__ ksa_m1_b,
    const float* __restrict__ ksa_m2_w, const float* __restrict__ ksa_m2_b,
    const float* __restrict__ up_dw_w, const float* __restrict__ up_dw_b,
    float* __restrict__ ws_dwu,   // (N, 32, H, W)
    float* __restrict__ ws_ksa)   // (N, 25, H, W)
{
    __shared__ float tile[TILE_ELEMS];
    __shared__ __hip_bfloat16 dwk_lds[NCH][256];  // relu(ksa-dw), per-thread cols

    const int tid = threadIdx.x;
    const int tx = tid & (TW - 1);
    const int ty = tid >> 5;
    const int tile_x = blockIdx.x * TW;
    const int tile_y = blockIdx.y * TH;
    const int n = blockIdx.z;
    const int x = tile_x + tx, y = tile_y + ty;
    const int pix = y * IMW + x;

    const float* upb = upper + (size_t)n * NCH * HW;
    float* dwu_out = ws_dwu + (size_t)n * NCH * HW + pix;

    // hoisted staging geometry (constant across chunks)
    int goff[LOADS];
    bool gok[LOADS];
    #pragma unroll
    for (int l = 0; l < LOADS; ++l) {
        const int idx = tid + l * 256;
        int c = idx / (HALO_H * HALO_W);
        int r = idx - c * (HALO_H * HALO_W);
        int hy = r / HALO_W, hx = r - hy * HALO_W;
        int gy = tile_y + hy - 2, gx = tile_x + hx - 2;
        gok[l] = (idx < TILE_ELEMS) && (gy >= 0) && (gy < IMH) && (gx >= 0) && (gx < IMW);
        goff[l] = c * HW + gy * IMW + gx;
    }

    float pre[LOADS];
    #pragma unroll
    for (int l = 0; l < LOADS; ++l)
        pre[l] = gok[l] ? upb[(size_t)0 + goff[l]] : 0.0f;

    #pragma unroll
    for (int ck = 0; ck < NCHUNK; ++ck) {
        __syncthreads();
        #pragma unroll
        for (int l = 0; l < LOADS; ++l) {
            const int idx = tid + l * 256;
            if (idx < TILE_ELEMS) tile[idx] = pre[l];
        }
        __syncthreads();
        if (ck + 1 < NCHUNK) {
            const size_t base = (size_t)(ck + 1) * CHUNK * HW;
            #pragma unroll
            for (int l = 0; l < LOADS; ++l)
                pre[l] = gok[l] ? upb[base + goff[l]] : 0.0f;
        }
        const int c0 = ck * CHUNK;
        #pragma unroll
        for (int cc = 0; cc < CHUNK; ++cc) {
            const int c = c0 + cc;
            float ak = ksa_dw_b[c];
            float au = up_dw_b[c];
            const float* tp = tile + cc * (HALO_H * HALO_W) + ty * HALO_W + tx;
            #pragma unroll
            for (int i = 0; i < KS; ++i)
                #pragma unroll
                for (int j = 0; j < KS; ++j) {
                    float wv = tp[i * HALO_W + j];
                    ak = fmaf(wv, ksa_dw_w[c * 25 + i * KS + j], ak);
                    au = fmaf(wv, up_dw_w[c * 25 + i * KS + j], au);
                }
            dwk_lds[c][tid] = __float2bfloat16(fmaxf(ak, 0.0f));  // retire to LDS
            dwu_out[(size_t)c * HW] = au;                          // retire to ws
        }
    }
    // dwk_lds: same-thread column access only -> no barrier needed.

    // Read back AFTER the pipeline; live range disjoint from staging state.
    float dwk[NCH];
    #pragma unroll
    for (int c = 0; c < NCH; ++c)
        dwk[c] = __bfloat162float(dwk_lds[c][tid]);

    // KSA MLP: 32 -> 50 (relu, runtime loop) -> 25 (sigmoid)
    float ksa[25];
    #pragma unroll
    for (int k = 0; k < 25; ++k) ksa[k] = ksa_m2_b[k];
    for (int h = 0; h < 50; ++h) {
        float hv = ksa_m1_b[h];
        #pragma unroll
        for (int c = 0; c < NCH; ++c)
            hv = fmaf(ksa_m1_w[h * NCH + c], dwk[c], hv);
        hv = fmaxf(hv, 0.0f);
        #pragma unroll
        for (int k = 0; k < 25; ++k)
            ksa[k] = fmaf(ksa_m2_w[k * 50 + h], hv, ksa[k]);
    }

    float* ksa_out = ws_ksa + (size_t)n * 25 * HW + pix;
    #pragma unroll
    for (int k = 0; k < 25; ++k)
        ksa_out[(size_t)k * HW] = sigmoidf_(ksa[k]);
}

// ---------------------------------------------------------------------------
// Kernel B: byte-identical to R7/R8 (T14 pipeline, CHUNK=4 — measured ~80-100us).
// ---------------------------------------------------------------------------
__global__ __launch_bounds__(256) void cika_low_up_kernel(
    const float* __restrict__ lower,
    const float* __restrict__ ws_ksa, const float* __restrict__ ws_dwu,
    const float* __restrict__ kca_dw_w, const float* __restrict__ kca_dw_b,
    const float* __restrict__ kca_m1_w, const float* __restrict__ kca_m1_b,
    const float* __restrict__ kca_m2_w, const float* __restrict__ kca_m2_b,
    const float* __restrict__ low_dyn_w, const float* __restrict__ low_dyn_b,
    const float* __restrict__ low_pw_w, const float* __restrict__ low_pw_b,
    const float* __restrict__ up_pw_w, const float* __restrict__ up_pw_b,
    float* __restrict__ out_low, float* __restrict__ out_up)
{
    __shared__ float tile[TILE_ELEMS];
    __shared__ __hip_bfloat16 td_lds[NCH][256];   // dynamic-dw result
    __shared__ __hip_bfloat16 dwl_lds[NCH][256];  // relu(kca-dw) result

    const int tid = threadIdx.x;
    const int tx = tid & (TW - 1);
    const int ty = tid >> 5;
    const int tile_x = blockIdx.x * TW;
    const int tile_y = blockIdx.y * TH;
    const int n = blockIdx.z;
    const int x = tile_x + tx, y = tile_y + ty;
    const int pix = y * IMW + x;

    const float* lob = lower + (size_t)n * NCH * HW;

    // hoisted staging geometry
    int goff[LOADS];
    bool gok[LOADS];
    #pragma unroll
    for (int l = 0; l < LOADS; ++l) {
        const int idx = tid + l * 256;
        int c = idx / (HALO_H * HALO_W);
        int r = idx - c * (HALO_H * HALO_W);
        int hy = r / HALO_W, hx = r - hy * HALO_W;
        int gy = tile_y + hy - 2, gx = tile_x + hx - 2;
        gok[l] = (idx < TILE_ELEMS) && (gy >= 0) && (gy < IMH) && (gx >= 0) && (gx < IMW);
        goff[l] = c * HW + gy * IMW + gx;
    }

    // ksa attention weights for this pixel (live through the lower pass only)
    float ksa[25];
    {
        const float* kp = ws_ksa + (size_t)n * 25 * HW + pix;
        #pragma unroll
        for (int k = 0; k < 25; ++k) ksa[k] = kp[(size_t)k * HW];
    }

    float pre[LOADS];
    #pragma unroll
    for (int l = 0; l < LOADS; ++l)
        pre[l] = gok[l] ? lob[(size_t)0 + goff[l]] : 0.0f;

    // ---- lower pass; results go straight to LDS ----
    #pragma unroll
    for (int ck = 0; ck < NCHUNK; ++ck) {
        __syncthreads();
        #pragma unroll
        for (int l = 0; l < LOADS; ++l) {
            const int idx = tid + l * 256;
            if (idx < TILE_ELEMS) tile[idx] = pre[l];
        }
        __syncthreads();
        if (ck + 1 < NCHUNK) {
            const size_t base = (size_t)(ck + 1) * CHUNK * HW;
            #pragma unroll
            for (int l = 0; l < LOADS; ++l)
                pre[l] = gok[l] ? lob[base + goff[l]] : 0.0f;
        }
        const int c0 = ck * CHUNK;
        #pragma unroll
        for (int cc = 0; cc < CHUNK; ++cc) {
            const int c = c0 + cc;
            float ad = kca_dw_b[c];
            float td = low_dyn_b[c];
            const float* tp = tile + cc * (HALO_H * HALO_W) + ty * HALO_W + tx;
            #pragma unroll
            for (int i = 0; i < KS; ++i)
                #pragma unroll
                for (int j = 0; j < KS; ++j) {
                    float wv = tp[i * HALO_W + j];
                    ad = fmaf(wv, kca_dw_w[c * 25 + i * KS + j], ad);
                    td = fmaf(wv * low_dyn_w[c * 25 + i * KS + j], ksa[i * KS + j], td);
                }
            dwl_lds[c][tid] = __float2bfloat16(fmaxf(ad, 0.0f));
            td_lds[c][tid]  = __float2bfloat16(td);
        }
    }
    // td_lds/dwl_lds are written and read only by column [.][tid] -> no barrier.

    // ---- out_low pointwise, chunked over output channels ----
    {
        float* ol = out_low + (size_t)n * NCH * HW + pix;
        #pragma unroll
        for (int oc = 0; oc < NCH / OC_CHUNK; ++oc) {
            float acc[OC_CHUNK];
            #pragma unroll
            for (int oo = 0; oo < OC_CHUNK; ++oo)
                acc[oo] = low_pw_b[oc * OC_CHUNK + oo];
            #pragma unroll
            for (int c = 0; c < NCH; ++c) {
                float v = __bfloat162float(td_lds[c][tid]);
                #pragma unroll
                for (int oo = 0; oo < OC_CHUNK; ++oo)
                    acc[oo] = fmaf(low_pw_w[(oc * OC_CHUNK + oo) * NCH + c], v, acc[oo]);
            }
            #pragma unroll
            for (int oo = 0; oo < OC_CHUNK; ++oo)
                ol[(size_t)(oc * OC_CHUNK + oo) * HW] = acc[oo];
        }
    }

    // ---- KCA MLP (stream dwl from LDS) ----
    float kca[NCH];
    {
        float hv[8];
        #pragma unroll
        for (int h = 0; h < 8; ++h) hv[h] = kca_m1_b[h];
        #pragma unroll
        for (int c = 0; c < NCH; ++c) {
            float v = __bfloat162float(dwl_lds[c][tid]);
            #pragma unroll
            for (int h = 0; h < 8; ++h)
                hv[h] = fmaf(kca_m1_w[h * NCH + c], v, hv[h]);
        }
        #pragma unroll
        for (int h = 0; h < 8; ++h) hv[h] = fmaxf(hv[h], 0.0f);
        #pragma unroll
        for (int k = 0; k < NCH; ++k) {
            float a = kca_m2_b[k];
            #pragma unroll
            for (int h = 0; h < 8; ++h)
                a = fmaf(kca_m2_w[k * 8 + h], hv[h], a);
            kca[k] = sigmoidf_(a);
        }
    }

    // ---- up path: gate dwu by kca, chunked pointwise ----
    float t2[NCH];
    {
        const float* dup = ws_dwu + (size_t)n * NCH * HW + pix;
        #pragma unroll
        for (int c = 0; c < NCH; ++c)
            t2[c] = dup[(size_t)c * HW] * kca[c];
    }
    {
        float* ou = out_up + (size_t)n * NCH * HW + pix;
        #pragma unroll
        for (int oc = 0; oc < NCH / OC_CHUNK; ++oc) {
            float acc[OC_CHUNK];
            #pragma unroll
            for (int oo = 0; oo < OC_CHUNK; ++oo)
                acc[oo] = up_pw_b[oc * OC_CHUNK + oo];
            #pragma unroll
            for (int c = 0; c < NCH; ++c) {
                #pragma unroll
                for (int oo = 0; oo < OC_CHUNK; ++oo)
                    acc[oo] = fmaf(up_pw_w[(oc * OC_CHUNK + oo) * NCH + c], t2[c], acc[oo]);
            }
            #pragma unroll
            for (int oo = 0; oo < OC_CHUNK; ++oo)
                ou[(size_t)(oc * OC_CHUNK + oo) * HW] = acc[oo];
        }
    }
}

extern "C" void kernel_launch(void* const* d_in, const int* in_sizes, int n_in,
                              void* d_out, int out_size, void* d_ws, size_t ws_size,
                              hipStream_t stream) {
    const float* lower    = (const float*)d_in[0];
    const float* upper    = (const float*)d_in[1];
    const float* kca_dw_w = (const float*)d_in[2];
    const float* kca_dw_b = (const float*)d_in[3];
    const float* kca_m1_w = (const float*)d_in[4];
    const float* kca_m1_b = (const float*)d_in[5];
    const float* kca_m2_w = (const float*)d_in[6];
    const float* kca_m2_b = (const float*)d_in[7];
    const float* ksa_dw_w = (const float*)d_in[8];
    const float* ksa_dw_b = (const float*)d_in[9];
    const float* ksa_m1_w = (const float*)d_in[10];
    const float* ksa_m1_b = (const float*)d_in[11];
    const float* ksa_m2_w = (const float*)d_in[12];
    const float* ksa_m2_b = (const float*)d_in[13];
    const float* low_dyn_w = (const float*)d_in[14];
    const float* low_dyn_b = (const float*)d_in[15];
    const float* low_pw_w  = (const float*)d_in[16];
    const float* low_pw_b  = (const float*)d_in[17];
    const float* up_dw_w   = (const float*)d_in[18];
    const float* up_dw_b   = (const float*)d_in[19];
    const float* up_pw_w   = (const float*)d_in[20];
    const float* up_pw_b   = (const float*)d_in[21];

    const int N = in_sizes[0] / (NCH * HW);
    float* out_low = (float*)d_out;
    float* out_up  = (float*)d_out + (size_t)N * NCH * HW;

    float* ws_dwu = (float*)d_ws;                       // N*32*HW floats
    float* ws_ksa = ws_dwu + (size_t)N * NCH * HW;      // N*25*HW floats

    dim3 grid(IMW / TW, IMH / TH, N);

    cika_ksa_kernel<<<grid, dim3(256), 0, stream>>>(
        upper,
        ksa_dw_w, ksa_dw_b, ksa_m1_w, ksa_m1_b, ksa_m2_w, ksa_m2_b,
        up_dw_w, up_dw_b,
        ws_dwu, ws_ksa);

    cika_low_up_kernel<<<grid, dim3(256), 0, stream>>>(
        lower, ws_ksa, ws_dwu,
        kca_dw_w, kca_dw_b, kca_m1_w, kca_m1_b, kca_m2_w, kca_m2_b,
        low_dyn_w, low_dyn_b, low_pw_w, low_pw_b,
        up_pw_w, up_pw_b,
        out_low, out_up);
}

// Round 10
// 114.734 us; speedup vs baseline: 7.7717x; 1.7373x over previous
//
#include <hip/hip_runtime.h>
#include <hip/hip_bf16.h>

#define KS 5
#define NCH 32
#define IMH 256
#define IMW 256
#define TW 32
#define TH 8
#define HALO_W (TW + 4)
#define HALO_H (TH + 4)
#define HW (IMH * IMW)
#define OC_CHUNK 8

#define CHUNK 4
#define NCHUNK (NCH / CHUNK)
#define TILE_ELEMS (CHUNK * HALO_H * HALO_W)
#define LOADS ((TILE_ELEMS + 255) / 256)   // 7

__device__ __forceinline__ float sigmoidf_(float x) {
    return 1.0f / (1.0f + __expf(-x));
}

// ---------------------------------------------------------------------------
// Fully fused CIKA forward, one kernel.
// Register discipline (proven R3-R9): per-channel results retire immediately
// to per-thread LDS columns; no register array is incrementally written
// across an UNROLLED staging loop. Chunk loops are ROLLED (#pragma unroll 1)
// so the online hv8[8] accumulator is ordinary loop-carried state (~8 regs).
// LDS: tile 6.9K + dwk/td (aliased) 16K + dwu 16K = 38.9 KB -> 4 blocks/CU;
// grid 1024 = fully resident (16 waves/CU). T14 prefetch in rolled form:
// next-chunk loads issue before compute, drain at next iteration's barrier.
// ---------------------------------------------------------------------------
__global__ __launch_bounds__(256) void cika_fused(
    const float* __restrict__ lower, const float* __restrict__ upper,
    const float* __restrict__ kca_dw_w, const float* __restrict__ kca_dw_b,
    const float* __restrict__ kca_m1_w, const float* __restrict__ kca_m1_b,
    const float* __restrict__ kca_m2_w, const float* __restrict__ kca_m2_b,
    const float* __restrict__ ksa_dw_w, const float* __restrict__ ksa_dw_b,
    const float* __restrict__ ksa_m1_w, const float* __restrict__ ksa_m1_b,
    const float* __restrict__ ksa_m2_w, const float* __restrict__ ksa_m2_b,
    const float* __restrict__ low_dyn_w, const float* __restrict__ low_dyn_b,
    const float* __restrict__ low_pw_w, const float* __restrict__ low_pw_b,
    const float* __restrict__ up_dw_w, const float* __restrict__ up_dw_b,
    const float* __restrict__ up_pw_w, const float* __restrict__ up_pw_b,
    float* __restrict__ out_low, float* __restrict__ out_up)
{
    __shared__ float tile[TILE_ELEMS];                 //  6912 B
    __shared__ __hip_bfloat16 dwk_td_lds[NCH][256];    // 16 KB: relu(ksa_dw), later td
    __shared__ __hip_bfloat16 dwu_lds[NCH][256];       // 16 KB: up_dw result

    const int tid = threadIdx.x;
    const int tx = tid & (TW - 1);
    const int ty = tid >> 5;
    const int tile_x = blockIdx.x * TW;
    const int tile_y = blockIdx.y * TH;
    const int n = blockIdx.z;
    const int x = tile_x + tx, y = tile_y + ty;
    const int pix = y * IMW + x;

    const float* lob = lower + (size_t)n * NCH * HW;
    const float* upb = upper + (size_t)n * NCH * HW;

    // hoisted staging geometry (shared by both passes)
    int goff[LOADS];
    bool gok[LOADS];
    #pragma unroll
    for (int l = 0; l < LOADS; ++l) {
        const int idx = tid + l * 256;
        int c = idx / (HALO_H * HALO_W);
        int r = idx - c * (HALO_H * HALO_W);
        int hy = r / HALO_W, hx = r - hy * HALO_W;
        int gy = tile_y + hy - 2, gx = tile_x + hx - 2;
        gok[l] = (idx < TILE_ELEMS) && (gy >= 0) && (gy < IMH) && (gx >= 0) && (gx < IMW);
        goff[l] = c * HW + gy * IMW + gx;
    }

    // ================= Phase 1: upper pass (rolled) =================
    {
        float pre[LOADS];
        #pragma unroll
        for (int l = 0; l < LOADS; ++l)
            pre[l] = gok[l] ? upb[(size_t)0 + goff[l]] : 0.0f;

        #pragma unroll 1
        for (int ck = 0; ck < NCHUNK; ++ck) {
            __syncthreads();
            #pragma unroll
            for (int l = 0; l < LOADS; ++l) {
                const int idx = tid + l * 256;
                if (idx < TILE_ELEMS) tile[idx] = pre[l];
            }
            __syncthreads();
            if (ck + 1 < NCHUNK) {
                const size_t base = (size_t)(ck + 1) * CHUNK * HW;
                #pragma unroll
                for (int l = 0; l < LOADS; ++l)
                    pre[l] = gok[l] ? upb[base + goff[l]] : 0.0f;
            }
            const int c0 = ck * CHUNK;
            #pragma unroll
            for (int cc = 0; cc < CHUNK; ++cc) {
                const int c = c0 + cc;
                float ak = ksa_dw_b[c];
                float au = up_dw_b[c];
                const float* tp = tile + cc * (HALO_H * HALO_W) + ty * HALO_W + tx;
                #pragma unroll
                for (int i = 0; i < KS; ++i)
                    #pragma unroll
                    for (int j = 0; j < KS; ++j) {
                        float wv = tp[i * HALO_W + j];
                        ak = fmaf(wv, ksa_dw_w[c * 25 + i * KS + j], ak);
                        au = fmaf(wv, up_dw_w[c * 25 + i * KS + j], au);
                    }
                dwk_td_lds[c][tid] = __float2bfloat16(fmaxf(ak, 0.0f));
                dwu_lds[c][tid]    = __float2bfloat16(au);
            }
        }
    }

    // ================= Phase 2: KSA MLP 32->50(relu)->25(sigmoid) =================
    float ksa[25];
    {
        float dwk[NCH];
        #pragma unroll
        for (int c = 0; c < NCH; ++c)
            dwk[c] = __bfloat162float(dwk_td_lds[c][tid]);
        #pragma unroll
        for (int k = 0; k < 25; ++k) ksa[k] = ksa_m2_b[k];
        for (int h = 0; h < 50; ++h) {
            float hv = ksa_m1_b[h];
            #pragma unroll
            for (int c = 0; c < NCH; ++c)
                hv = fmaf(ksa_m1_w[h * NCH + c], dwk[c], hv);
            hv = fmaxf(hv, 0.0f);
            #pragma unroll
            for (int k = 0; k < 25; ++k)
                ksa[k] = fmaf(ksa_m2_w[k * 50 + h], hv, ksa[k]);
        }
        #pragma unroll
        for (int k = 0; k < 25; ++k) ksa[k] = sigmoidf_(ksa[k]);
    }
    // dwk_td_lds is now dead as dwk -> reused below for td (same-thread
    // column access only, so no barrier needed for the aliasing).

    // ================= Phase 3: lower pass (rolled), online hv8 =================
    float hv8[8];
    #pragma unroll
    for (int h = 0; h < 8; ++h) hv8[h] = kca_m1_b[h];
    {
        float pre[LOADS];
        #pragma unroll
        for (int l = 0; l < LOADS; ++l)
            pre[l] = gok[l] ? lob[(size_t)0 + goff[l]] : 0.0f;

        #pragma unroll 1
        for (int ck = 0; ck < NCHUNK; ++ck) {
            __syncthreads();
            #pragma unroll
            for (int l = 0; l < LOADS; ++l) {
                const int idx = tid + l * 256;
                if (idx < TILE_ELEMS) tile[idx] = pre[l];
            }
            __syncthreads();
            if (ck + 1 < NCHUNK) {
                const size_t base = (size_t)(ck + 1) * CHUNK * HW;
                #pragma unroll
                for (int l = 0; l < LOADS; ++l)
                    pre[l] = gok[l] ? lob[base + goff[l]] : 0.0f;
            }
            const int c0 = ck * CHUNK;
            #pragma unroll
            for (int cc = 0; cc < CHUNK; ++cc) {
                const int c = c0 + cc;
                float ad = kca_dw_b[c];
                float td = low_dyn_b[c];
                const float* tp = tile + cc * (HALO_H * HALO_W) + ty * HALO_W + tx;
                #pragma unroll
                for (int i = 0; i < KS; ++i)
                    #pragma unroll
                    for (int j = 0; j < KS; ++j) {
                        float wv = tp[i * HALO_W + j];
                        ad = fmaf(wv, kca_dw_w[c * 25 + i * KS + j], ad);
                        td = fmaf(wv * low_dyn_w[c * 25 + i * KS + j], ksa[i * KS + j], td);
                    }
                ad = fmaxf(ad, 0.0f);
                #pragma unroll
                for (int h = 0; h < 8; ++h)
                    hv8[h] = fmaf(kca_m1_w[h * NCH + c], ad, hv8[h]);
                dwk_td_lds[c][tid] = __float2bfloat16(td);   // td into aliased array
            }
        }
    }

    // ================= Phase 4: out_low = low_pw @ td + b =================
    {
        float tdv[NCH];
        #pragma unroll
        for (int c = 0; c < NCH; ++c)
            tdv[c] = __bfloat162float(dwk_td_lds[c][tid]);
        float* ol = out_low + (size_t)n * NCH * HW + pix;
        #pragma unroll
        for (int oc = 0; oc < NCH / OC_CHUNK; ++oc) {
            float acc[OC_CHUNK];
            #pragma unroll
            for (int oo = 0; oo < OC_CHUNK; ++oo)
                acc[oo] = low_pw_b[oc * OC_CHUNK + oo];
            #pragma unroll
            for (int c = 0; c < NCH; ++c)
                #pragma unroll
                for (int oo = 0; oo < OC_CHUNK; ++oo)
                    acc[oo] = fmaf(low_pw_w[(oc * OC_CHUNK + oo) * NCH + c], tdv[c], acc[oo]);
            #pragma unroll
            for (int oo = 0; oo < OC_CHUNK; ++oo)
                ol[(size_t)(oc * OC_CHUNK + oo) * HW] = acc[oo];
        }
    }

    // ================= Phase 5: KCA finish =================
    float kca[NCH];
    #pragma unroll
    for (int h = 0; h < 8; ++h) hv8[h] = fmaxf(hv8[h], 0.0f);
    #pragma unroll
    for (int k = 0; k < NCH; ++k) {
        float a = kca_m2_b[k];
        #pragma unroll
        for (int h = 0; h < 8; ++h)
            a = fmaf(kca_m2_w[k * 8 + h], hv8[h], a);
        kca[k] = sigmoidf_(a);
    }

    // ================= Phase 6: up path =================
    {
        float t2[NCH];
        #pragma unroll
        for (int c = 0; c < NCH; ++c)
            t2[c] = __bfloat162float(dwu_lds[c][tid]) * kca[c];
        float* ou = out_up + (size_t)n * NCH * HW + pix;
        #pragma unroll
        for (int oc = 0; oc < NCH / OC_CHUNK; ++oc) {
            float acc[OC_CHUNK];
            #pragma unroll
            for (int oo = 0; oo < OC_CHUNK; ++oo)
                acc[oo] = up_pw_b[oc * OC_CHUNK + oo];
            #pragma unroll
            for (int c = 0; c < NCH; ++c)
                #pragma unroll
                for (int oo = 0; oo < OC_CHUNK; ++oo)
                    acc[oo] = fmaf(up_pw_w[(oc * OC_CHUNK + oo) * NCH + c], t2[c], acc[oo]);
            #pragma unroll
            for (int oo = 0; oo < OC_CHUNK; ++oo)
                ou[(size_t)(oc * OC_CHUNK + oo) * HW] = acc[oo];
        }
    }
}

extern "C" void kernel_launch(void* const* d_in, const int* in_sizes, int n_in,
                              void* d_out, int out_size, void* d_ws, size_t ws_size,
                              hipStream_t stream) {
    const float* lower    = (const float*)d_in[0];
    const float* upper    = (const float*)d_in[1];
    const float* kca_dw_w = (const float*)d_in[2];
    const float* kca_dw_b = (const float*)d_in[3];
    const float* kca_m1_w = (const float*)d_in[4];
    const float* kca_m1_b = (const float*)d_in[5];
    const float* kca_m2_w = (const float*)d_in[6];
    const float* kca_m2_b = (const float*)d_in[7];
    const float* ksa_dw_w = (const float*)d_in[8];
    const float* ksa_dw_b = (const float*)d_in[9];
    const float* ksa_m1_w = (const float*)d_in[10];
    const float* ksa_m1_b = (const float*)d_in[11];
    const float* ksa_m2_w = (const float*)d_in[12];
    const float* ksa_m2_b = (const float*)d_in[13];
    const float* low_dyn_w = (const float*)d_in[14];
    const float* low_dyn_b = (const float*)d_in[15];
    const float* low_pw_w  = (const float*)d_in[16];
    const float* low_pw_b  = (const float*)d_in[17];
    const float* up_dw_w   = (const float*)d_in[18];
    const float* up_dw_b   = (const float*)d_in[19];
    const float* up_pw_w   = (const float*)d_in[20];
    const float* up_pw_b   = (const float*)d_in[21];

    const int N = in_sizes[0] / (NCH * HW);
    float* out_low = (float*)d_out;
    float* out_up  = (float*)d_out + (size_t)N * NCH * HW;

    dim3 grid(IMW / TW, IMH / TH, N);
    cika_fused<<<grid, dim3(256), 0, stream>>>(
        lower, upper,
        kca_dw_w, kca_dw_b, kca_m1_w, kca_m1_b, kca_m2_w, kca_m2_b,
        ksa_dw_w, ksa_dw_b, ksa_m1_w, ksa_m1_b, ksa_m2_w, ksa_m2_b,
        low_dyn_w, low_dyn_b, low_pw_w, low_pw_b,
        up_dw_w, up_dw_b, up_pw_w, up_pw_b,
        out_low, out_up);
}